// Round 14
// baseline (383.453 us; speedup 1.0000x reference)
//
#include <hip/hip_runtime.h>
#include <hip/hip_bf16.h>
#include <hip/hip_cooperative_groups.h>
#include <cstdint>
#include <cstddef>

namespace cg = cooperative_groups;

// ---------- types ----------
typedef __attribute__((ext_vector_type(4))) float f32x4;
typedef __attribute__((ext_vector_type(8))) short s16x8;
typedef __attribute__((ext_vector_type(4))) unsigned short u16x4;

__device__ __forceinline__ unsigned short f2bf(float f) {
    union { float f; unsigned u; } v; v.f = f;
    unsigned u = v.u;
    u += 0x7fffu + ((u >> 16) & 1u);      // round-to-nearest-even
    return (unsigned short)(u >> 16);
}
__device__ __forceinline__ float lo_f(unsigned v) {
    union { unsigned u; float f; } w; w.u = v << 16; return w.f;
}
__device__ __forceinline__ float hi_f(unsigned v) {
    union { unsigned u; float f; } w; w.u = v & 0xffff0000u; return w.f;
}

// =====================================================================
// Network is LINEAR: out_pre = pooled @ Wbig + bbig,
//   Wbig = W1 @ W2 @ [Wc|Wr],  bbig = ((b1@W2)+b2)@[Wc|Wr] + [bc|br].
// Round-14: cooperative mega-kernel, launch-proofed (256 blocks = 1/CU,
// LDS ~17KB, VGPR<=256) + CHECKED launch with multi-kernel fallback
// reusing the same device functions (deterministic either way).
// pooled k' ordering: pooled[n][bin*512+c] <-> W1 row (c*49+bin).
// =====================================================================

struct MP {
    const float* fm; const int* roi;
    const float* W1; const float* b1; const float* W2; const float* b2;
    const float* Wc; const float* bc; const float* Wr; const float* br;
    float* out;
    unsigned short* pooled; unsigned short* fmT; unsigned short* WfT;
    float* Wf16; float* bfv; float* bbig;
    float* partial1; float* partial2;
    unsigned short* WbigT; float* partialG;
    unsigned* counter;
};

// ---------- P0 unit: vb<1056 fm-transpose (64p x 32c); else skinny W2 ----------
__device__ void p0_unit(const MP& p, int vb, int t) {
    if (vb < 1056) {
        __shared__ float tile[32][65];
        const int p0 = (vb % 66) * 64, c0 = (vb / 66) * 32;
        {
            const int pp = t & 63, cc = t >> 6;      // 64 x 8
            #pragma unroll
            for (int k = 0; k < 4; ++k) {
                int c = c0 + cc + 8 * k;
                if (p0 + pp < 4200) tile[cc + 8 * k][pp] = p.fm[(size_t)c * 4200 + p0 + pp];
            }
        }
        __syncthreads();
        {
            const int c = t & 31, pr = t >> 5;       // 32 x 16
            #pragma unroll
            for (int k = 0; k < 4; ++k) {
                int pp = p0 + pr + 16 * k;
                if (pp < 4200) p.fmT[(size_t)pp * 512 + c0 + c] = f2bf(tile[c][pr + 16 * k]);
            }
        }
        __syncthreads();
    } else {
        const int v = vb - 1056;                     // 0..255
        const int bx = v & 31, ky = v >> 5;
        const int lane = t & 63, wave = t >> 6;
        const int r0 = bx * 128 + wave * 16;
        const int k0 = ky * 512;
        const int lr = lane & 15, lks = lane >> 4;
        const float* ap = p.W2 + (size_t)(r0 + lr) * 4096 + k0 + lks * 8;
        f32x4 acc = {0.f, 0.f, 0.f, 0.f};
        for (int s = 0; s < 16; ++s) {
            f32x4 f0 = *(const f32x4*)(ap + s * 32);
            f32x4 f1 = *(const f32x4*)(ap + s * 32 + 4);
            union { unsigned short us[8]; s16x8 v; } a, b;
            const int i0 = k0 + s * 32 + lks * 8;
            #pragma unroll
            for (int e = 0; e < 8; ++e) {
                int i = i0 + e;
                float bv = (lr < 3) ? p.Wc[i * 3 + lr] : (lr < 15) ? p.Wr[i * 12 + lr - 3] : 0.f;
                b.us[e] = f2bf(bv);
            }
            a.us[0] = f2bf(f0.x); a.us[1] = f2bf(f0.y);
            a.us[2] = f2bf(f0.z); a.us[3] = f2bf(f0.w);
            a.us[4] = f2bf(f1.x); a.us[5] = f2bf(f1.y);
            a.us[6] = f2bf(f1.z); a.us[7] = f2bf(f1.w);
            acc = __builtin_amdgcn_mfma_f32_16x16x32_bf16(a.v, b.v, acc, 0, 0, 0);
        }
        const int row = r0 + (lane >> 4) * 4;
        float* op = p.partial1 + ((size_t)ky * 4096 + row) * 16 + lr;
        #pragma unroll
        for (int q = 0; q < 4; ++q) op[q * 16] = acc[q];
    }
}

// ---------- P1 unit: vb<128 reduce partial1 -> Wf16/WfT; vb==128 bfv ----------
__device__ void p1_unit(const MP& p, int vb, int t) {
    const int lane = t & 63, wv = t >> 6;
    if (vb < 128) {
        int idx = vb * 512 + t;
        float s = 0.f;
        #pragma unroll
        for (int sp = 0; sp < 8; ++sp) s += p.partial1[sp * 65536 + idx];
        p.Wf16[idx] = s;
        int i = idx >> 4, j = idx & 15;
        p.WfT[(size_t)j * 4096 + i] = f2bf(s);
    } else {
        __shared__ float red15[8][15];
        float acc[15];
        #pragma unroll
        for (int j = 0; j < 15; ++j) acc[j] = 0.f;
        for (int i = t; i < 4096; i += 512) {
            float bv = p.b2[i];
            #pragma unroll
            for (int j = 0; j < 15; ++j)
                acc[j] += bv * ((j < 3) ? p.Wc[i * 3 + j] : p.Wr[i * 12 + (j - 3)]);
        }
        #pragma unroll
        for (int j = 0; j < 15; ++j) {
            float x = acc[j];
            #pragma unroll
            for (int off = 32; off >= 1; off >>= 1) x += __shfl_xor(x, off, 64);
            if (lane == 0) red15[wv][j] = x;
        }
        __syncthreads();
        if (t < 15) {
            float s = 0.f;
            #pragma unroll
            for (int w = 0; w < 8; ++w) s += red15[w][t];
            p.bfv[t] = s + ((t < 3) ? p.bc[t] : p.br[t - 3]);
        }
        __syncthreads();
    }
}

// ---------- P2 unit: r5<3 skinny W1; else pool ----------
#define PB(NH, NW) { \
    uint2 v[NH * NW]; \
    _Pragma("unroll") for (int r = 0; r < NH; ++r) \
        _Pragma("unroll") for (int s = 0; s < NW; ++s) \
            v[r * NW + s] = *(const uint2*)(base + ho[r] + wo[s]); \
    float a0 = lo_f(v[0].x), a1 = hi_f(v[0].x); \
    float a2 = lo_f(v[0].y), a3 = hi_f(v[0].y); \
    _Pragma("unroll") for (int q = 1; q < NH * NW; ++q) { \
        a0 = fmaxf(a0, lo_f(v[q].x)); a1 = fmaxf(a1, hi_f(v[q].x)); \
        a2 = fmaxf(a2, lo_f(v[q].y)); a3 = fmaxf(a3, hi_f(v[q].y)); } \
    m0 = a0; m1 = a1; m2 = a2; m3 = a3; } break;

__device__ void p2_unit(const MP& p, int vb, int t) {
    const int g5 = vb / 5, r5 = vb % 5;
    if (r5 < 3) {
        const int sb = g5 * 3 + r5;
        if (sb >= 1568) return;
        const int bx = sb % 196, ky = sb / 196;
        const int lane = t & 63, wave = t >> 6;
        const int r0 = bx * 128 + wave * 16;
        const int k0 = ky * 512;
        const int lr = lane & 15, lks = lane >> 4;
        const float* ap = p.W1 + (size_t)(r0 + lr) * 4096 + k0 + lks * 8;
        const unsigned short* bp = p.WfT + (size_t)lr * 4096 + k0 + lks * 8;
        f32x4 acc = {0.f, 0.f, 0.f, 0.f};
        #pragma unroll 4
        for (int s = 0; s < 16; ++s) {
            f32x4 f0 = __builtin_nontemporal_load((const f32x4*)(ap + s * 32));
            f32x4 f1 = __builtin_nontemporal_load((const f32x4*)(ap + s * 32 + 4));
            s16x8 b = *(const s16x8*)(bp + s * 32);
            union { unsigned short us[8]; s16x8 v; } a;
            a.us[0] = f2bf(f0.x); a.us[1] = f2bf(f0.y);
            a.us[2] = f2bf(f0.z); a.us[3] = f2bf(f0.w);
            a.us[4] = f2bf(f1.x); a.us[5] = f2bf(f1.y);
            a.us[6] = f2bf(f1.z); a.us[7] = f2bf(f1.w);
            acc = __builtin_amdgcn_mfma_f32_16x16x32_bf16(a.v, b, acc, 0, 0, 0);
        }
        const int row = r0 + (lane >> 4) * 4;
        float* op = p.partial2 + ((size_t)ky * 25088 + row) * 16 + lr;
        #pragma unroll
        for (int q = 0; q < 4; ++q) __builtin_nontemporal_store(acc[q], op + q * 16);
    } else {
        const int n = g5 * 2 + (r5 - 3);
        if (n >= 1024) return;
        __shared__ int hoff[7][5], woff[7][5], hcnt[7], wcnt[7];
        if (t == 0) {
            int x0 = p.roi[n*4+0] / 16, y0 = p.roi[n*4+1] / 16;
            int x1 = p.roi[n*4+2] / 16, y1 = p.roi[n*4+3] / 16;
            if (x1 - x0 <= 1) { if (x1 < 84) x1 += 1; else x0 -= 1; }
            if (y1 - y0 <= 1) { if (y1 < 50) y1 += 1; else y0 -= 1; }
            int xs = min(max(x0, 0), 84), xe = min(max(x1, 0), 84);
            int ys = min(max(y0, 0), 50), ye = min(max(y1, 0), 50);
            int Lx = xe - xs, Ly = ye - ys;
            #pragma unroll
            for (int i = 0; i < 7; ++i) {
                int b0 = ys + (i * Ly) / 7, b1 = ys + ((i + 1) * Ly + 6) / 7;
                hcnt[i] = min(b1, b0 + 5) - b0;
                int c0 = xs + (i * Lx) / 7, c1 = xs + ((i + 1) * Lx + 6) / 7;
                wcnt[i] = min(c1, c0 + 5) - c0;
                #pragma unroll
                for (int q = 0; q < 5; ++q) {
                    hoff[i][q] = (b0 + q) * 43008;
                    woff[i][q] = (c0 + q) * 512;
                }
            }
        }
        __syncthreads();
        const int g = t >> 7;
        const int c4 = (t & 127) * 4;
        const unsigned short* base = p.fmT + c4;
        unsigned short* orow = p.pooled + (size_t)n * 25088;
        for (int bp = 0; bp < 13; ++bp) {
            int bin = bp * 4 + g;
            if (bin < 49) {
                int bi = bin / 7, bj = bin - bi * 7;
                int ho[5], wo[5];
                #pragma unroll
                for (int q = 0; q < 5; ++q) { ho[q] = hoff[bi][q]; wo[q] = woff[bj][q]; }
                int nh = hcnt[bi], nw = wcnt[bj];
                float m0, m1, m2, m3;
                switch ((nh - 1) * 5 + (nw - 1)) {
                    case  0: PB(1,1)  case  1: PB(1,2)  case  2: PB(1,3)
                    case  3: PB(1,4)  case  4: PB(1,5)
                    case  5: PB(2,1)  case  6: PB(2,2)  case  7: PB(2,3)
                    case  8: PB(2,4)  case  9: PB(2,5)
                    case 10: PB(3,1)  case 11: PB(3,2)  case 12: PB(3,3)
                    case 13: PB(3,4)  case 14: PB(3,5)
                    case 15: PB(4,1)  case 16: PB(4,2)  case 17: PB(4,3)
                    case 18: PB(4,4)  case 19: PB(4,5)
                    case 20: PB(5,1)  case 21: PB(5,2)  case 22: PB(5,3)
                    case 23: PB(5,4)  case 24: PB(5,5)
                    default: m0 = m1 = m2 = m3 = 0.f; break;
                }
                u16x4 o;
                o.x = f2bf(m0); o.y = f2bf(m1); o.z = f2bf(m2); o.w = f2bf(m3);
                __builtin_nontemporal_store(o, (u16x4*)(orow + bin * 512 + c4));
            }
        }
        __syncthreads();
    }
}

// ---------- P3 unit: vb<49 reduce partial2 -> WbigT (k'-permuted); vb==49 bbig ----
__device__ void p3_unit(const MP& p, int vb, int t) {
    const int lane = t & 63, wv = t >> 6;
    if (vb < 49) {
        const int r = vb * 512 + t;
        float sj[16];
        #pragma unroll
        for (int j = 0; j < 16; ++j) sj[j] = 0.f;
        #pragma unroll
        for (int sp = 0; sp < 8; ++sp) {
            const float4* pp = (const float4*)(p.partial2 + ((size_t)sp * 25088 + r) * 16);
            float4 a = pp[0], b = pp[1], c = pp[2], d = pp[3];
            sj[0] += a.x; sj[1] += a.y; sj[2]  += a.z; sj[3]  += a.w;
            sj[4] += b.x; sj[5] += b.y; sj[6]  += b.z; sj[7]  += b.w;
            sj[8] += c.x; sj[9] += c.y; sj[10] += c.z; sj[11] += c.w;
            sj[12] += d.x; sj[13] += d.y; sj[14] += d.z; sj[15] += d.w;
        }
        const int c = r / 49, bin = r - c * 49;
        const int pk = bin * 512 + c;
        #pragma unroll
        for (int j = 0; j < 16; ++j)
            p.WbigT[(size_t)j * 25088 + pk] = f2bf(sj[j]);
    } else {
        __shared__ float red15b[8][15];
        float acc[15];
        #pragma unroll
        for (int j = 0; j < 15; ++j) acc[j] = 0.f;
        for (int i = t; i < 4096; i += 512) {
            float bv = p.b1[i];
            #pragma unroll
            for (int j = 0; j < 15; ++j) acc[j] += bv * p.Wf16[i * 16 + j];
        }
        #pragma unroll
        for (int j = 0; j < 15; ++j) {
            float x = acc[j];
            #pragma unroll
            for (int off = 32; off >= 1; off >>= 1) x += __shfl_xor(x, off, 64);
            if (lane == 0) red15b[wv][j] = x;
        }
        __syncthreads();
        if (t < 16) {
            float s = 0.f;
            if (t < 15) {
                #pragma unroll
                for (int w = 0; w < 8; ++w) s += red15b[w][t];
                s += p.bfv[t];
            }
            p.bbig[t] = s;
        }
        __syncthreads();
    }
}

// ---------- P4 unit: final GEMM (512 units = 64 m-tiles x 8 kz) ----------
__device__ void p4_unit(const MP& p, int vb, int t) {
    __shared__ float redG[8][64][4];
    const int lane = t & 63, wv = t >> 6;
    const int m0 = (vb & 63) * 16, kz = vb >> 6;
    const int lr = lane & 15, lks = lane >> 4;
    f32x4 acc = {0.f, 0.f, 0.f, 0.f};
    const unsigned short* arow = p.pooled + (size_t)(m0 + lr) * 25088 + kz * 3136 + lks * 8;
    const unsigned short* brow = p.WbigT + (size_t)lr * 25088 + kz * 3136 + lks * 8;
    for (int s = wv; s < 98; s += 8) {
        s16x8 a = __builtin_nontemporal_load((const s16x8*)(arow + s * 32));
        s16x8 b = *(const s16x8*)(brow + s * 32);
        acc = __builtin_amdgcn_mfma_f32_16x16x32_bf16(a, b, acc, 0, 0, 0);
    }
    #pragma unroll
    for (int r = 0; r < 4; ++r) redG[wv][lane][r] = acc[r];
    __syncthreads();
    if (wv == 0) {
        #pragma unroll
        for (int r = 0; r < 4; ++r) {
            float s = 0.f;
            #pragma unroll
            for (int w = 0; w < 8; ++w) s += redG[w][lane][r];
            int row = m0 + (lane >> 4) * 4 + r;
            p.partialG[((size_t)kz * 1024 + row) * 16 + (lane & 15)] = s;
        }
    }
    __syncthreads();
}

// ---------- P5 unit: finalize ----------
__device__ void p5_unit(const MP& p, int vb, int t) {
    const int m = vb * 512 + t;
    float v[15];
    #pragma unroll
    for (int j = 0; j < 15; ++j) v[j] = p.bbig[j];
    for (int kz = 0; kz < 8; ++kz) {
        const float* pp = p.partialG + ((size_t)kz * 1024 + m) * 16;
        #pragma unroll
        for (int j = 0; j < 15; ++j) v[j] += pp[j];
    }
    float mx = fmaxf(v[0], fmaxf(v[1], v[2]));
    float e0 = expf(v[0] - mx), e1 = expf(v[1] - mx), e2 = expf(v[2] - mx);
    float inv = 1.f / (e0 + e1 + e2);
    p.out[m * 3 + 0] = e0 * inv;
    p.out[m * 3 + 1] = e1 * inv;
    p.out[m * 3 + 2] = e2 * inv;
    #pragma unroll
    for (int j = 3; j < 15; ++j) p.out[3072 + m * 12 + (j - 3)] = v[j];
}

// ---------- cooperative mega ----------
__global__ __launch_bounds__(512, 2) void mega(MP p) {
    cg::grid_group grid = cg::this_grid();
    const int t = threadIdx.x;
    const int bid = blockIdx.x, nb = gridDim.x;
    __shared__ int svb;

    if (bid == 0 && t == 0) *p.counter = 0;
    for (int vb = bid; vb < 1312; vb += nb) p0_unit(p, vb, t);
    grid.sync();
    for (int vb = bid; vb < 129; vb += nb) p1_unit(p, vb, t);
    grid.sync();
    while (true) {                                 // work-stolen P2
        if (t == 0) svb = (int)atomicAdd(p.counter, 1u);
        __syncthreads();
        const int vb = svb;
        if (vb >= 2615) break;
        p2_unit(p, vb, t);
        __syncthreads();
    }
    grid.sync();
    for (int vb = bid; vb < 50; vb += nb) p3_unit(p, vb, t);
    grid.sync();
    for (int vb = bid; vb < 512; vb += nb) p4_unit(p, vb, t);
    grid.sync();
    for (int vb = bid; vb < 2; vb += nb) p5_unit(p, vb, t);
}

// ---------- fallback kernels (one phase each, static block assignment) ----------
__global__ __launch_bounds__(512) void fb0(MP p) {
    if (blockIdx.x == 0 && threadIdx.x == 0) *p.counter = 0;
    p0_unit(p, blockIdx.x, threadIdx.x);
}
__global__ __launch_bounds__(512) void fb1(MP p) { p1_unit(p, blockIdx.x, threadIdx.x); }
__global__ __launch_bounds__(512) void fb2(MP p) { p2_unit(p, blockIdx.x, threadIdx.x); }
__global__ __launch_bounds__(512) void fb3(MP p) { p3_unit(p, blockIdx.x, threadIdx.x); }
__global__ __launch_bounds__(512) void fb4(MP p) { p4_unit(p, blockIdx.x, threadIdx.x); }
__global__ __launch_bounds__(512) void fb5(MP p) { p5_unit(p, blockIdx.x, threadIdx.x); }

// ---------- launch ----------
extern "C" void kernel_launch(void* const* d_in, const int* in_sizes, int n_in,
                              void* d_out, int out_size, void* d_ws, size_t ws_size,
                              hipStream_t stream) {
    char* ws = (char*)d_ws;
    MP p;
    p.fm   = (const float*)d_in[0];
    p.roi  = (const int*)d_in[1];
    p.W1   = (const float*)d_in[2];
    p.b1   = (const float*)d_in[3];
    p.W2   = (const float*)d_in[4];
    p.b2   = (const float*)d_in[5];
    p.Wc   = (const float*)d_in[6];
    p.bc   = (const float*)d_in[7];
    p.Wr   = (const float*)d_in[8];
    p.br   = (const float*)d_in[9];
    p.out  = (float*)d_out;
    p.pooled   = (unsigned short*)(ws);                  //  51,380,224  [1024][25088] bf16 (k')
    p.fmT      = (unsigned short*)(ws + 51380224);       //   4,300,800  [4200][512] bf16
    p.WfT      = (unsigned short*)(ws + 55681024);       //     131,072  [16][4096] bf16
    p.Wf16     = (float*)         (ws + 55812096);       //     262,144  [4096][16] f32
    p.bfv      = (float*)         (ws + 56074240);       //          64
    p.bbig     = (float*)         (ws + 56074304);       //          64
    p.counter  = (unsigned*)      (ws + 56074368);       //          64
    p.partial1 = (float*)         (ws + 56074432);       //   4,194,304  [8][4096][16] f32
    p.partial2 = (float*)         (ws + 60268800);       //  51,380,224  [8][25088][16] f32
    p.WbigT    = (unsigned short*)(ws + 111649024);      //     802,816  [16][25088] bf16 (k')
    p.partialG = (float*)         (ws + 112451840);      //     524,288  [8][1024][16] f32

    void* kargs[] = { &p };
    hipError_t err = hipLaunchCooperativeKernel((const void*)mega, dim3(256),
                                                dim3(512), kargs, 0, stream);
    if (err != hipSuccess) {
        (void)hipGetLastError();                 // clear error state
        fb0<<<1312, 512, 0, stream>>>(p);
        fb1<<<129, 512, 0, stream>>>(p);
        fb2<<<2615, 512, 0, stream>>>(p);
        fb3<<<50, 512, 0, stream>>>(p);
        fb4<<<512, 512, 0, stream>>>(p);
        fb5<<<2, 512, 0, stream>>>(p);
    }
}

// Round 15
// 225.549 us; speedup vs baseline: 1.7001x; 1.7001x over previous
//
#include <hip/hip_runtime.h>
#include <hip/hip_bf16.h>
#include <cstdint>
#include <cstddef>

// ---------- types ----------
typedef __attribute__((ext_vector_type(4))) float f32x4;
typedef __attribute__((ext_vector_type(8))) short s16x8;
typedef __attribute__((ext_vector_type(4))) unsigned short u16x4;

__device__ __forceinline__ unsigned short f2bf(float f) {
    union { float f; unsigned u; } v; v.f = f;
    unsigned u = v.u;
    u += 0x7fffu + ((u >> 16) & 1u);      // round-to-nearest-even
    return (unsigned short)(u >> 16);
}
__device__ __forceinline__ float lo_f(unsigned v) {
    union { unsigned u; float f; } w; w.u = v << 16; return w.f;
}
__device__ __forceinline__ float hi_f(unsigned v) {
    union { unsigned u; float f; } w; w.u = v & 0xffff0000u; return w.f;
}

// =====================================================================
// Network is LINEAR: out_pre = pooled @ Wbig + bbig,
//   Wbig = W1 @ W2 @ [Wc|Wr],  bbig = ((b1@W2)+b2)@[Wc|Wr] + [bc|br].
// Round-15: static 6-dispatch pipeline.  KEY CHANGE (from r14 coop
// counters: W1 stream is per-wave LATENCY-bound, BW ~ resident waves):
// megaB uses 256-thread blocks (84-VGPR skinny -> 5-6 waves/SIMD vs 4
// at 512-thr) to raise waves/CU ~1.5x.  prep_wcat dropped (direct
// Wc/Wr gather in skinny W2, verified r14).
// pooled k' ordering: pooled[n][bin*512+c] <-> W1 row (c*49+bin).
// =====================================================================

// ---------- 1. prepA: fm transpose (1056u) ∥ skinny W2 direct-gather (256u) ----
__global__ __launch_bounds__(512) void prepA(
        const float* __restrict__ fm, unsigned short* __restrict__ fmT,
        const float* __restrict__ W2, const float* __restrict__ Wc,
        const float* __restrict__ Wr, float* __restrict__ partial1) {
    const int g5 = blockIdx.x / 5, r5 = blockIdx.x % 5;
    const int t = threadIdx.x;
    if (r5 < 4) {
        const int unit = g5 * 4 + r5;            // 0..1055
        if (unit >= 1056) return;
        __shared__ float tile[2][32][33];
        const int sub = t >> 8, tt = t & 255;
        const int tid = unit * 2 + sub;          // 0..2111
        const int p0 = (tid % 132) * 32, c0 = (tid / 132) * 32;
        const int tx = tt & 31, ty = tt >> 5;
        #pragma unroll
        for (int yy = ty; yy < 32; yy += 8) {
            int p = p0 + tx;
            if (p < 4200) tile[sub][yy][tx] = fm[(size_t)(c0 + yy) * 4200 + p];
        }
        __syncthreads();
        #pragma unroll
        for (int yy = ty; yy < 32; yy += 8) {
            int p = p0 + yy;
            if (p < 4200) fmT[(size_t)p * 512 + c0 + tx] = f2bf(tile[sub][tx][yy]);
        }
    } else {
        const int v = g5;                        // 0..255
        if (v >= 256) return;
        const int bx = v & 31, ky = v >> 5;
        const int lane = t & 63, wave = t >> 6;
        const int r0 = bx * 128 + wave * 16;
        const int k0 = ky * 512;
        const int lr = lane & 15, lks = lane >> 4;
        const float* ap = W2 + (size_t)(r0 + lr) * 4096 + k0 + lks * 8;
        f32x4 acc = {0.f, 0.f, 0.f, 0.f};
        for (int s = 0; s < 16; ++s) {
            f32x4 f0 = *(const f32x4*)(ap + s * 32);
            f32x4 f1 = *(const f32x4*)(ap + s * 32 + 4);
            union { unsigned short us[8]; s16x8 v; } a, b;
            const int i0 = k0 + s * 32 + lks * 8;
            #pragma unroll
            for (int e = 0; e < 8; ++e) {
                int i = i0 + e;
                float bv = (lr < 3) ? Wc[i * 3 + lr] : (lr < 15) ? Wr[i * 12 + lr - 3] : 0.f;
                b.us[e] = f2bf(bv);
            }
            a.us[0] = f2bf(f0.x); a.us[1] = f2bf(f0.y);
            a.us[2] = f2bf(f0.z); a.us[3] = f2bf(f0.w);
            a.us[4] = f2bf(f1.x); a.us[5] = f2bf(f1.y);
            a.us[6] = f2bf(f1.z); a.us[7] = f2bf(f1.w);
            acc = __builtin_amdgcn_mfma_f32_16x16x32_bf16(a.v, b.v, acc, 0, 0, 0);
        }
        const int row = r0 + (lane >> 4) * 4;
        float* op = partial1 + ((size_t)ky * 4096 + row) * 16 + lr;
        #pragma unroll
        for (int q = 0; q < 4; ++q) op[q * 16] = acc[q];
    }
}

// ---------- 2. reduce partial1 -> Wf16 f32 + WfT bf16; block 256: bfv ----------
__global__ __launch_bounds__(256) void reduce_wf(
        const float* __restrict__ partial1, const float* __restrict__ b2,
        const float* __restrict__ Wc, const float* __restrict__ Wr,
        const float* __restrict__ bc, const float* __restrict__ br,
        float* __restrict__ Wf16, unsigned short* __restrict__ WfT,
        float* __restrict__ bfv) {
    const int t = threadIdx.x;
    if (blockIdx.x < 256) {
        int idx = blockIdx.x * 256 + t;          // over 65536
        float s = 0.f;
        #pragma unroll
        for (int sp = 0; sp < 8; ++sp) s += partial1[sp * 65536 + idx];
        Wf16[idx] = s;
        int i = idx >> 4, j = idx & 15;
        WfT[(size_t)j * 4096 + i] = f2bf(s);     // row 15 stays zero
    } else {
        float acc[15];
        #pragma unroll
        for (int j = 0; j < 15; ++j) acc[j] = 0.f;
        for (int i = t; i < 4096; i += 256) {
            float bv = b2[i];
            #pragma unroll
            for (int j = 0; j < 15; ++j)
                acc[j] += bv * ((j < 3) ? Wc[i * 3 + j] : Wr[i * 12 + (j - 3)]);
        }
        const int lane = t & 63, wv = t >> 6;
        __shared__ float red[4][15];
        #pragma unroll
        for (int j = 0; j < 15; ++j) {
            float x = acc[j];
            #pragma unroll
            for (int off = 32; off >= 1; off >>= 1) x += __shfl_xor(x, off, 64);
            if (lane == 0) red[wv][j] = x;
        }
        __syncthreads();
        if (t < 15)
            bfv[t] = red[0][t] + red[1][t] + red[2][t] + red[3][t]
                   + ((t < 3) ? bc[t] : br[t - 3]);
    }
}

// ---------- 3. megaB (256 thr): skinny W1 (3136u, 64-row blocks) ∥ pool (1024u) ----
#define PB(NH, NW) { \
    uint2 v[NH * NW]; \
    _Pragma("unroll") for (int r = 0; r < NH; ++r) \
        _Pragma("unroll") for (int s = 0; s < NW; ++s) \
            v[r * NW + s] = *(const uint2*)(base + ho[r] + wo[s]); \
    float a0 = lo_f(v[0].x), a1 = hi_f(v[0].x); \
    float a2 = lo_f(v[0].y), a3 = hi_f(v[0].y); \
    _Pragma("unroll") for (int q = 1; q < NH * NW; ++q) { \
        a0 = fmaxf(a0, lo_f(v[q].x)); a1 = fmaxf(a1, hi_f(v[q].x)); \
        a2 = fmaxf(a2, lo_f(v[q].y)); a3 = fmaxf(a3, hi_f(v[q].y)); } \
    m0 = a0; m1 = a1; m2 = a2; m3 = a3; } break;

__global__ __launch_bounds__(256) void megaB(
        const unsigned short* __restrict__ fmT, const int* __restrict__ roi,
        unsigned short* __restrict__ pooled,
        const float* __restrict__ W1, const unsigned short* __restrict__ WfT,
        float* __restrict__ partial2) {
    const int g4 = blockIdx.x >> 2, r4 = blockIdx.x & 3;
    const int t = threadIdx.x;
    if (r4 < 3) {
        // ---- skinny W1: 4 waves x 16 rows = 64 rows per block ----
        const int sb = g4 * 3 + r4;
        if (sb >= 3136) return;
        const int bx = sb % 392, ky = sb / 392;
        const int lane = t & 63, wave = t >> 6;      // wave 0..3
        const int r0 = bx * 64 + wave * 16;
        const int k0 = ky * 512;
        const int lr = lane & 15, lks = lane >> 4;
        const float* ap = W1 + (size_t)(r0 + lr) * 4096 + k0 + lks * 8;
        const unsigned short* bp = WfT + (size_t)lr * 4096 + k0 + lks * 8;
        f32x4 acc = {0.f, 0.f, 0.f, 0.f};
        #pragma unroll 4
        for (int s = 0; s < 16; ++s) {
            f32x4 f0 = __builtin_nontemporal_load((const f32x4*)(ap + s * 32));
            f32x4 f1 = __builtin_nontemporal_load((const f32x4*)(ap + s * 32 + 4));
            s16x8 b = *(const s16x8*)(bp + s * 32);
            union { unsigned short us[8]; s16x8 v; } a;
            a.us[0] = f2bf(f0.x); a.us[1] = f2bf(f0.y);
            a.us[2] = f2bf(f0.z); a.us[3] = f2bf(f0.w);
            a.us[4] = f2bf(f1.x); a.us[5] = f2bf(f1.y);
            a.us[6] = f2bf(f1.z); a.us[7] = f2bf(f1.w);
            acc = __builtin_amdgcn_mfma_f32_16x16x32_bf16(a.v, b, acc, 0, 0, 0);
        }
        const int row = r0 + (lane >> 4) * 4;
        float* op = partial2 + ((size_t)ky * 25088 + row) * 16 + lr;
        #pragma unroll
        for (int q = 0; q < 4; ++q) __builtin_nontemporal_store(acc[q], op + q * 16);
    } else {
        // ---- pool block (one ROI), r8 pool4 geometry: 2 groups x 128 thr ----
        const int n = g4;
        if (n >= 1024) return;
        __shared__ int hoff[7][5], woff[7][5], hcnt[7], wcnt[7];
        if (t == 0) {
            int x0 = roi[n*4+0] / 16, y0 = roi[n*4+1] / 16;
            int x1 = roi[n*4+2] / 16, y1 = roi[n*4+3] / 16;
            if (x1 - x0 <= 1) { if (x1 < 84) x1 += 1; else x0 -= 1; }
            if (y1 - y0 <= 1) { if (y1 < 50) y1 += 1; else y0 -= 1; }
            int xs = min(max(x0, 0), 84), xe = min(max(x1, 0), 84);
            int ys = min(max(y0, 0), 50), ye = min(max(y1, 0), 50);
            int Lx = xe - xs, Ly = ye - ys;
            #pragma unroll
            for (int i = 0; i < 7; ++i) {
                int b0 = ys + (i * Ly) / 7, b1 = ys + ((i + 1) * Ly + 6) / 7;
                hcnt[i] = min(b1, b0 + 5) - b0;
                int c0 = xs + (i * Lx) / 7, c1 = xs + ((i + 1) * Lx + 6) / 7;
                wcnt[i] = min(c1, c0 + 5) - c0;
                #pragma unroll
                for (int q = 0; q < 5; ++q) {
                    hoff[i][q] = (b0 + q) * 43008;
                    woff[i][q] = (c0 + q) * 512;
                }
            }
        }
        __syncthreads();
        const int g = t >> 7;                 // 2 bin groups
        const int c4 = (t & 127) * 4;
        const unsigned short* base = fmT + c4;
        unsigned short* orow = pooled + (size_t)n * 25088;
        for (int bp = 0; bp < 25; ++bp) {
            int bin = bp * 2 + g;
            if (bin < 49) {
                int bi = bin / 7, bj = bin - bi * 7;
                int ho[5], wo[5];
                #pragma unroll
                for (int q = 0; q < 5; ++q) { ho[q] = hoff[bi][q]; wo[q] = woff[bj][q]; }
                int nh = hcnt[bi], nw = wcnt[bj];
                float m0, m1, m2, m3;
                switch ((nh - 1) * 5 + (nw - 1)) {
                    case  0: PB(1,1)  case  1: PB(1,2)  case  2: PB(1,3)
                    case  3: PB(1,4)  case  4: PB(1,5)
                    case  5: PB(2,1)  case  6: PB(2,2)  case  7: PB(2,3)
                    case  8: PB(2,4)  case  9: PB(2,5)
                    case 10: PB(3,1)  case 11: PB(3,2)  case 12: PB(3,3)
                    case 13: PB(3,4)  case 14: PB(3,5)
                    case 15: PB(4,1)  case 16: PB(4,2)  case 17: PB(4,3)
                    case 18: PB(4,4)  case 19: PB(4,5)
                    case 20: PB(5,1)  case 21: PB(5,2)  case 22: PB(5,3)
                    case 23: PB(5,4)  case 24: PB(5,5)
                    default: m0 = m1 = m2 = m3 = 0.f; break;
                }
                u16x4 o;
                o.x = f2bf(m0); o.y = f2bf(m1); o.z = f2bf(m2); o.w = f2bf(m3);
                __builtin_nontemporal_store(o, (u16x4*)(orow + bin * 512 + c4));
            }
        }
    }
}

// ---------- 4. reduce partial2 (8 splits) -> WbigT bf16 (k'-permuted); +bbig ----
__global__ __launch_bounds__(256) void reduce_wbig(
        const float* __restrict__ partial2, const float* __restrict__ Wf16,
        const float* __restrict__ bfv, const float* __restrict__ b1,
        unsigned short* __restrict__ WbigT, float* __restrict__ bbig) {
    const int t = threadIdx.x;
    if (blockIdx.x < 98) {
        const int r = blockIdx.x * 256 + t;      // W1 row (linear)
        float sj[16];
        #pragma unroll
        for (int j = 0; j < 16; ++j) sj[j] = 0.f;
        #pragma unroll
        for (int sp = 0; sp < 8; ++sp) {
            const float4* pp = (const float4*)(partial2 + ((size_t)sp * 25088 + r) * 16);
            float4 a = pp[0], b = pp[1], c = pp[2], d = pp[3];
            sj[0] += a.x; sj[1] += a.y; sj[2]  += a.z; sj[3]  += a.w;
            sj[4] += b.x; sj[5] += b.y; sj[6]  += b.z; sj[7]  += b.w;
            sj[8] += c.x; sj[9] += c.y; sj[10] += c.z; sj[11] += c.w;
            sj[12] += d.x; sj[13] += d.y; sj[14] += d.z; sj[15] += d.w;
        }
        const int c = r / 49, bin = r - c * 49;
        const int p = bin * 512 + c;             // k' index
        #pragma unroll
        for (int j = 0; j < 16; ++j)
            WbigT[(size_t)j * 25088 + p] = f2bf(sj[j]);
    } else {
        float acc[15];
        #pragma unroll
        for (int j = 0; j < 15; ++j) acc[j] = 0.f;
        for (int i = t; i < 4096; i += 256) {
            float bv = b1[i];
            #pragma unroll
            for (int j = 0; j < 15; ++j) acc[j] += bv * Wf16[i * 16 + j];
        }
        const int lane = t & 63, wv = t >> 6;
        __shared__ float red[4][15];
        #pragma unroll
        for (int j = 0; j < 15; ++j) {
            float x = acc[j];
            #pragma unroll
            for (int off = 32; off >= 1; off >>= 1) x += __shfl_xor(x, off, 64);
            if (lane == 0) red[wv][j] = x;
        }
        __syncthreads();
        if (t < 16) {
            float s = 0.f;
            if (t < 15)
                s = red[0][t] + red[1][t] + red[2][t] + red[3][t] + bfv[t];
            bbig[t] = s;
        }
    }
}

// ---------- 5. final GEMM: pooled @ WbigT^T -> partialG[8][1024][16] ----------
__global__ __launch_bounds__(256) void final_gemm(
        const unsigned short* __restrict__ pooled,
        const unsigned short* __restrict__ WbigT,
        float* __restrict__ partialG) {
    const int t = threadIdx.x, lane = t & 63, wave = t >> 6;
    const int m0 = blockIdx.x * 16, kz = blockIdx.y;
    const int lr = lane & 15, lks = lane >> 4;
    f32x4 acc = {0.f, 0.f, 0.f, 0.f};
    const unsigned short* arow = pooled + (size_t)(m0 + lr) * 25088 + kz * 3136 + lks * 8;
    const unsigned short* brow = WbigT + (size_t)lr * 25088 + kz * 3136 + lks * 8;
    for (int s = wave; s < 98; s += 4) {
        s16x8 a = __builtin_nontemporal_load((const s16x8*)(arow + s * 32));
        s16x8 b = *(const s16x8*)(brow + s * 32);
        acc = __builtin_amdgcn_mfma_f32_16x16x32_bf16(a, b, acc, 0, 0, 0);
    }
    __shared__ float red[4][64][4];
    #pragma unroll
    for (int r = 0; r < 4; ++r) red[wave][lane][r] = acc[r];
    __syncthreads();
    if (wave == 0) {
        #pragma unroll
        for (int r = 0; r < 4; ++r) {
            float s = red[0][lane][r] + red[1][lane][r] + red[2][lane][r] + red[3][lane][r];
            int row = m0 + (lane >> 4) * 4 + r;
            partialG[((size_t)kz * 1024 + row) * 16 + (lane & 15)] = s;
        }
    }
}

// ---------- 6. finalize: sum 8 partials + bbig, softmax(3), write out ----------
__global__ __launch_bounds__(256) void finalize_kernel(
        const float* __restrict__ partialG, const float* __restrict__ bbig,
        float* __restrict__ out) {
    const int m = blockIdx.x * 256 + threadIdx.x;   // 0..1023
    float v[15];
    #pragma unroll
    for (int j = 0; j < 15; ++j) v[j] = bbig[j];
    for (int kz = 0; kz < 8; ++kz) {
        const float* p = partialG + ((size_t)kz * 1024 + m) * 16;
        #pragma unroll
        for (int j = 0; j < 15; ++j) v[j] += p[j];
    }
    float mx = fmaxf(v[0], fmaxf(v[1], v[2]));
    float e0 = expf(v[0] - mx), e1 = expf(v[1] - mx), e2 = expf(v[2] - mx);
    float inv = 1.f / (e0 + e1 + e2);
    out[m * 3 + 0] = e0 * inv;
    out[m * 3 + 1] = e1 * inv;
    out[m * 3 + 2] = e2 * inv;
    #pragma unroll
    for (int j = 3; j < 15; ++j) out[3072 + m * 12 + (j - 3)] = v[j];
}

// ---------- launch ----------
extern "C" void kernel_launch(void* const* d_in, const int* in_sizes, int n_in,
                              void* d_out, int out_size, void* d_ws, size_t ws_size,
                              hipStream_t stream) {
    const float* featmap = (const float*)d_in[0];
    const int*   roi     = (const int*)d_in[1];
    const float* W1      = (const float*)d_in[2];
    const float* b1      = (const float*)d_in[3];
    const float* W2      = (const float*)d_in[4];
    const float* b2      = (const float*)d_in[5];
    const float* Wc      = (const float*)d_in[6];
    const float* bc      = (const float*)d_in[7];
    const float* Wr      = (const float*)d_in[8];
    const float* br      = (const float*)d_in[9];
    float* out = (float*)d_out;

    // workspace layout (bytes, 16-aligned)
    char* ws = (char*)d_ws;
    unsigned short* pooled   = (unsigned short*)(ws);                //  51,380,224  [1024][25088] bf16 (k')
    unsigned short* fmT      = (unsigned short*)(ws + 51380224);     //   4,300,800  [4200][512] bf16
    unsigned short* WfT      = (unsigned short*)(ws + 55681024);     //     131,072  [16][4096] bf16
    float*          Wf16     = (float*)        (ws + 55812096);      //     262,144  [4096][16] f32
    float*          bfv      = (float*)        (ws + 56074240);      //          64
    float*          bbig     = (float*)        (ws + 56074304);      //          64
    float*          partial1 = (float*)        (ws + 56074432);      //   4,194,304  [8][4096][16] f32
    float*          partial2 = (float*)        (ws + 60268800);      //  51,380,224  [8][25088][16] f32 (r-order)
    unsigned short* WbigT    = (unsigned short*)(ws + 111649024);    //     802,816  [16][25088] bf16 (k'-order)
    float*          partialG = (float*)        (ws + 112451840);     //     524,288  [8][1024][16] f32

    prepA<<<1320, 512, 0, stream>>>(featmap, fmT, W2, Wc, Wr, partial1);
    reduce_wf<<<257, 256, 0, stream>>>(partial1, b2, Wc, Wr, bc, br, Wf16, WfT, bfv);
    megaB<<<4184, 256, 0, stream>>>(fmT, roi, pooled, W1, WfT, partial2);
    reduce_wbig<<<99, 256, 0, stream>>>(partial2, Wf16, bfv, b1, WbigT, bbig);
    final_gemm<<<dim3(64, 8), 256, 0, stream>>>(pooled, WbigT, partialG);
    finalize_kernel<<<4, 256, 0, stream>>>(partialG, bbig, out);
}